// Round 1
// baseline (182.268 us; speedup 1.0000x reference)
//
#include <hip/hip_runtime.h>
#include <hip/hip_bf16.h>
#include <math.h>

#define NROW 8192
#define DIM  128
#define BM   128
#define BN   128
#define KC   32
#define NT   (NROW / BM)   // 64 tiles per dim

// ---- online logsumexp helpers ----
__device__ __forceinline__ void lse_acc(float x, float& m, float& s) {
    float M = fmaxf(m, x);
    s = s * __expf(m - M) + __expf(x - M);
    m = M;
}

__device__ __forceinline__ void lse_merge(float& m, float& s, float mo, float so) {
    float M = fmaxf(m, mo);
    s = s * __expf(m - M) + so * __expf(mo - M);
    m = M;
}

// ---- Kernel A: per-row inverse L2 norm ----
__global__ __launch_bounds__(256)
void norms_kernel(const float* __restrict__ f, float* __restrict__ invn) {
    int row  = blockIdx.x * 4 + (threadIdx.x >> 6);
    int lane = threadIdx.x & 63;
    float2 v = *(const float2*)(f + row * DIM + lane * 2);
    float ss = v.x * v.x + v.y * v.y;
    #pragma unroll
    for (int off = 32; off; off >>= 1) ss += __shfl_xor(ss, off, 64);
    if (lane == 0) {
        float nrm = fmaxf(sqrtf(ss), 1e-12f);
        invn[row] = 1.0f / nrm;
    }
}

// ---- Kernel B: tiled sim + fused circle-loss logits + per-block LSE ----
__global__ __launch_bounds__(256, 4)
void sim_kernel(const float* __restrict__ f, const int* __restrict__ lab,
                const float* __restrict__ invn, float4* __restrict__ blockRes) {
    const int tc = blockIdx.x;   // col tile
    const int tr = blockIdx.y;   // row tile
    const int bid = tr * NT + tc;
    const int tid = threadIdx.x;

    if (tc < tr) {  // lower triangle: write neutral element and exit
        if (tid == 0) blockRes[bid] = make_float4(-1e30f, 0.f, -1e30f, 0.f);
        return;
    }

    __shared__ float As[KC][BM + 4];
    __shared__ float Bs[KC][BN + 4];
    __shared__ int   labA[BM];
    __shared__ int   labB[BN];
    __shared__ float red[4][4];

    const int rowBase = tr * BM;
    const int colBase = tc * BN;

    if (tid < BM) labA[tid] = lab[rowBase + tid];
    else          labB[tid - BM] = lab[colBase + tid - BM];

    float acc[8][8];
    #pragma unroll
    for (int i = 0; i < 8; ++i)
        #pragma unroll
        for (int j = 0; j < 8; ++j) acc[i][j] = 0.f;

    const int ty = tid >> 4;   // 0..15
    const int tx = tid & 15;   // 0..15

    for (int kc = 0; kc < DIM / KC; ++kc) {
        // ---- stage A and B tiles (transposed, normalized) ----
        #pragma unroll
        for (int it = 0; it < 4; ++it) {
            int idx = it * 256 + tid;     // 0..1023
            int r   = idx >> 3;           // 0..127
            int c4  = idx & 7;            // 0..7
            const float4 va = *(const float4*)(f + (size_t)(rowBase + r) * DIM + kc * KC + c4 * 4);
            float sa = invn[rowBase + r];
            As[c4 * 4 + 0][r] = va.x * sa;
            As[c4 * 4 + 1][r] = va.y * sa;
            As[c4 * 4 + 2][r] = va.z * sa;
            As[c4 * 4 + 3][r] = va.w * sa;
            const float4 vb = *(const float4*)(f + (size_t)(colBase + r) * DIM + kc * KC + c4 * 4);
            float sb = invn[colBase + r];
            Bs[c4 * 4 + 0][r] = vb.x * sb;
            Bs[c4 * 4 + 1][r] = vb.y * sb;
            Bs[c4 * 4 + 2][r] = vb.z * sb;
            Bs[c4 * 4 + 3][r] = vb.w * sb;
        }
        __syncthreads();

        // ---- 8x8 micro-tile FMA ----
        for (int k = 0; k < KC; ++k) {
            float4 a0 = *(const float4*)&As[k][ty * 8];
            float4 a1 = *(const float4*)&As[k][ty * 8 + 4];
            float4 b0 = *(const float4*)&Bs[k][tx * 8];
            float4 b1 = *(const float4*)&Bs[k][tx * 8 + 4];
            float av[8] = {a0.x, a0.y, a0.z, a0.w, a1.x, a1.y, a1.z, a1.w};
            float bv[8] = {b0.x, b0.y, b0.z, b0.w, b1.x, b1.y, b1.z, b1.w};
            #pragma unroll
            for (int ii = 0; ii < 8; ++ii)
                #pragma unroll
                for (int jj = 0; jj < 8; ++jj)
                    acc[ii][jj] = fmaf(av[ii], bv[jj], acc[ii][jj]);
        }
        __syncthreads();
    }

    // ---- fused epilogue: logits + online LSE ----
    float mp = -1e30f, sp = 0.f, mn = -1e30f, sn = 0.f;
    const bool diag = (tr == tc);
    #pragma unroll
    for (int ii = 0; ii < 8; ++ii) {
        int ig = rowBase + ty * 8 + ii;
        int li = labA[ty * 8 + ii];
        #pragma unroll
        for (int jj = 0; jj < 8; ++jj) {
            int jg = colBase + tx * 8 + jj;
            if (diag && jg <= ig) continue;   // strict upper triangle only
            float s = acc[ii][jj];
            if (li == labB[tx * 8 + jj]) {
                float apv = fmaxf(1.25f - s, 0.f);
                lse_acc(apv * (0.75f - s) * 256.f, mp, sp);
            } else {
                float anv = fmaxf(s + 0.25f, 0.f);
                lse_acc(anv * (s - 0.25f) * 256.f, mn, sn);
            }
        }
    }

    // ---- block reduction ----
    #pragma unroll
    for (int off = 32; off; off >>= 1) {
        float mo = __shfl_xor(mp, off, 64), so = __shfl_xor(sp, off, 64);
        lse_merge(mp, sp, mo, so);
        float mo2 = __shfl_xor(mn, off, 64), so2 = __shfl_xor(sn, off, 64);
        lse_merge(mn, sn, mo2, so2);
    }
    int wid = tid >> 6;
    if ((tid & 63) == 0) {
        red[wid][0] = mp; red[wid][1] = sp; red[wid][2] = mn; red[wid][3] = sn;
    }
    __syncthreads();
    if (tid == 0) {
        mp = red[0][0]; sp = red[0][1]; mn = red[0][2]; sn = red[0][3];
        #pragma unroll
        for (int w = 1; w < 4; ++w) {
            lse_merge(mp, sp, red[w][0], red[w][1]);
            lse_merge(mn, sn, red[w][2], red[w][3]);
        }
        blockRes[bid] = make_float4(mp, sp, mn, sn);
    }
}

// ---- Kernel C: final reduction + softplus ----
__global__ __launch_bounds__(256)
void finalize_kernel(const float4* __restrict__ blockRes, int nb, float* __restrict__ out) {
    __shared__ float red[4][4];
    int tid = threadIdx.x;
    float mp = -1e30f, sp = 0.f, mn = -1e30f, sn = 0.f;
    for (int i = tid; i < nb; i += 256) {
        float4 v = blockRes[i];
        lse_merge(mp, sp, v.x, v.y);
        lse_merge(mn, sn, v.z, v.w);
    }
    #pragma unroll
    for (int off = 32; off; off >>= 1) {
        float mo = __shfl_xor(mp, off, 64), so = __shfl_xor(sp, off, 64);
        lse_merge(mp, sp, mo, so);
        float mo2 = __shfl_xor(mn, off, 64), so2 = __shfl_xor(sn, off, 64);
        lse_merge(mn, sn, mo2, so2);
    }
    int wid = tid >> 6;
    if ((tid & 63) == 0) {
        red[wid][0] = mp; red[wid][1] = sp; red[wid][2] = mn; red[wid][3] = sn;
    }
    __syncthreads();
    if (tid == 0) {
        mp = red[0][0]; sp = red[0][1]; mn = red[0][2]; sn = red[0][3];
        #pragma unroll
        for (int w = 1; w < 4; ++w) {
            lse_merge(mp, sp, red[w][0], red[w][1]);
            lse_merge(mn, sn, red[w][2], red[w][3]);
        }
        float lse_p = (sp > 0.f) ? mp + logf(sp) : -1e30f;
        float lse_n = (sn > 0.f) ? mn + logf(sn) : -1e30f;
        float x = lse_p + lse_n;
        float r = (x > 20.f) ? x : log1pf(expf(x));
        out[0] = r;
    }
}

extern "C" void kernel_launch(void* const* d_in, const int* in_sizes, int n_in,
                              void* d_out, int out_size, void* d_ws, size_t ws_size,
                              hipStream_t stream) {
    const float* f   = (const float*)d_in[0];
    const int*   lab = (const int*)d_in[1];
    float*  out      = (float*)d_out;

    float*  invn     = (float*)d_ws;                                  // 8192 floats
    float4* blockRes = (float4*)((char*)d_ws + NROW * sizeof(float)); // 4096 float4

    norms_kernel<<<NROW / 4, 256, 0, stream>>>(f, invn);

    dim3 grid(NT, NT);
    sim_kernel<<<grid, 256, 0, stream>>>(f, lab, invn, blockRes);

    finalize_kernel<<<1, 256, 0, stream>>>(blockRes, NT * NT, out);
}

// Round 2
// 88.217 us; speedup vs baseline: 2.0661x; 2.0661x over previous
//
#include <hip/hip_runtime.h>
#include <hip/hip_bf16.h>
#include <math.h>

#define NROW 8192
#define DIM  128
#define BM   128
#define BN   128
#define KCH  64            // K chunk staged in LDS
#define NT   (NROW / BM)   // 64 tiles per dim

typedef __bf16 bf16x8 __attribute__((ext_vector_type(8)));
typedef float  f32x4  __attribute__((ext_vector_type(4)));

// ---- online logsumexp helpers ----
__device__ __forceinline__ void lse_acc(float x, float& m, float& s) {
    float M = fmaxf(m, x);
    s = s * __expf(m - M) + __expf(x - M);
    m = M;
}

__device__ __forceinline__ void lse_merge(float& m, float& s, float mo, float so) {
    float M = fmaxf(m, mo);
    s = s * __expf(m - M) + so * __expf(mo - M);
    m = M;
}

// ---- Kernel A: normalize rows, split fp32 -> hi/lo bf16 ----
__global__ __launch_bounds__(256)
void prep_kernel(const float* __restrict__ f,
                 __hip_bfloat16* __restrict__ fhi,
                 __hip_bfloat16* __restrict__ flo) {
    int row  = blockIdx.x * 4 + (threadIdx.x >> 6);
    int lane = threadIdx.x & 63;
    float2 v = ((const float2*)(f + (size_t)row * DIM))[lane];
    float ss = v.x * v.x + v.y * v.y;
    #pragma unroll
    for (int off = 32; off; off >>= 1) ss += __shfl_xor(ss, off, 64);
    float inv = 1.0f / fmaxf(sqrtf(ss), 1e-12f);
    float x0 = v.x * inv, x1 = v.y * inv;
    __hip_bfloat16 h0 = __float2bfloat16(x0);
    __hip_bfloat16 h1 = __float2bfloat16(x1);
    __hip_bfloat16 l0 = __float2bfloat16(x0 - __bfloat162float(h0));
    __hip_bfloat16 l1 = __float2bfloat16(x1 - __bfloat162float(h1));
    __hip_bfloat162 hv; hv.x = h0; hv.y = h1;
    __hip_bfloat162 lv; lv.x = l0; lv.y = l1;
    ((__hip_bfloat162*)(fhi + (size_t)row * DIM))[lane] = hv;
    ((__hip_bfloat162*)(flo + (size_t)row * DIM))[lane] = lv;
}

// ---- Kernel B: MFMA sim (hi/lo split) + fused circle-loss LSE ----
__global__ __launch_bounds__(512, 4)
void sim_kernel(const __hip_bfloat16* __restrict__ fhi,
                const __hip_bfloat16* __restrict__ flo,
                const int* __restrict__ lab,
                float4* __restrict__ blockRes) {
    const int tc  = blockIdx.x;   // col tile
    const int tr  = blockIdx.y;   // row tile
    const int bid = tr * NT + tc;
    const int tid = threadIdx.x;

    if (tc < tr) {  // lower triangle: neutral element
        if (tid == 0) blockRes[bid] = make_float4(-1e30f, 0.f, -1e30f, 0.f);
        return;
    }

    // 4 arrays of [128 rows][64 bf16] = 16 KB each: Ahi, Alo, Bhi, Blo
    __shared__ __align__(16) char smem[4 * 16384];
    __shared__ int labA[BM];
    __shared__ int labB[BN];
    __shared__ float red[8][4];

    const int rowBase = tr * BM;
    const int colBase = tc * BN;
    const int w    = tid >> 6;    // wave 0..7
    const int lane = tid & 63;

    if (tid < BM)            labA[tid] = lab[rowBase + tid];
    else if (tid < BM + BN)  labB[tid - BM] = lab[colBase + tid - BM];

    f32x4 acc[4][2];
    #pragma unroll
    for (int mi = 0; mi < 4; ++mi)
        #pragma unroll
        for (int ni = 0; ni < 2; ++ni) acc[mi][ni] = (f32x4){0.f, 0.f, 0.f, 0.f};

    const int mrow0 = (w >> 2) * 64;   // wave M band (2 rows of waves)
    const int ncol0 = (w & 3) * 32;    // wave N band (4 cols of waves)
    const int lrow  = lane & 15;
    const int lk    = lane >> 4;

    // per-lane staging constants: within a 1KB segment lane covers
    // row = 8*seg16 + (lane>>3), kb_linear = (lane&7)*16
    // source byte offset pre-swizzled so LDS stays linear (rule 21):
    const int kbs = 16 * ((lane & 7) ^ (lane >> 3));
    const int rsub = lane >> 3;  // row within 8-row segment

    for (int kc = 0; kc < DIM / KCH; ++kc) {
        // ---- stage 64KB via global_load_lds (8 issues/wave) ----
        #pragma unroll
        for (int t = 0; t < 8; ++t) {
            int seg = w * 8 + t;          // 0..63
            int arr = seg >> 4;           // 0:Ahi 1:Alo 2:Bhi 3:Blo
            int s16 = seg & 15;           // 8-row segment within array
            char* ldsb = smem + arr * 16384 + s16 * 1024;
            int row  = s16 * 8 + rsub;
            int grow = ((arr < 2) ? rowBase : colBase) + row;
            const char* gb = (const char*)(((arr & 1) == 0) ? fhi : flo);
            const char* g  = gb + (size_t)grow * (DIM * 2) + kc * (KCH * 2) + kbs;
            __builtin_amdgcn_global_load_lds(
                (const __attribute__((address_space(1))) void*)g,
                (__attribute__((address_space(3))) void*)ldsb, 16, 0, 0);
        }
        __syncthreads();   // compiler drains vmcnt before barrier

        const char* Ahi = smem;
        const char* Alo = smem + 16384;
        const char* Bhi = smem + 2 * 16384;
        const char* Blo = smem + 3 * 16384;

        #pragma unroll
        for (int c = 0; c < 2; ++c) {     // K=32 steps within chunk
            int kb = c * 64 + lk * 16;
            bf16x8 bh[2], bl[2];
            #pragma unroll
            for (int ni = 0; ni < 2; ++ni) {
                int rb = ncol0 + ni * 16 + lrow;
                int ab = rb * 128 + (kb ^ ((rb & 7) << 4));
                bh[ni] = *(const bf16x8*)(Bhi + ab);
                bl[ni] = *(const bf16x8*)(Blo + ab);
            }
            #pragma unroll
            for (int mi = 0; mi < 4; ++mi) {
                int ra = mrow0 + mi * 16 + lrow;
                int aa = ra * 128 + (kb ^ ((ra & 7) << 4));
                bf16x8 ah = *(const bf16x8*)(Ahi + aa);
                bf16x8 al = *(const bf16x8*)(Alo + aa);
                #pragma unroll
                for (int ni = 0; ni < 2; ++ni) {
                    acc[mi][ni] = __builtin_amdgcn_mfma_f32_16x16x32_bf16(ah, bh[ni], acc[mi][ni], 0, 0, 0);
                    acc[mi][ni] = __builtin_amdgcn_mfma_f32_16x16x32_bf16(ah, bl[ni], acc[mi][ni], 0, 0, 0);
                    acc[mi][ni] = __builtin_amdgcn_mfma_f32_16x16x32_bf16(al, bh[ni], acc[mi][ni], 0, 0, 0);
                }
            }
        }
        __syncthreads();   // before next chunk overwrites LDS
    }

    // ---- fused epilogue: logits + online LSE ----
    float mp = -1e30f, sp = 0.f, mn = -1e30f, sn = 0.f;
    const bool diag = (tr == tc);
    #pragma unroll
    for (int mi = 0; mi < 4; ++mi) {
        #pragma unroll
        for (int ni = 0; ni < 2; ++ni) {
            #pragma unroll
            for (int r = 0; r < 4; ++r) {
                int il = mrow0 + mi * 16 + lk * 4 + r;   // local row
                int jl = ncol0 + ni * 16 + lrow;         // local col
                if (diag && jl <= il) continue;          // strict upper triangle
                float s = acc[mi][ni][r];
                if (labA[il] == labB[jl]) {
                    float apv = fmaxf(1.25f - s, 0.f);
                    lse_acc(apv * (0.75f - s) * 256.f, mp, sp);
                } else {
                    float anv = fmaxf(s + 0.25f, 0.f);
                    lse_acc(anv * (s - 0.25f) * 256.f, mn, sn);
                }
            }
        }
    }

    // ---- block reduction (8 waves) ----
    #pragma unroll
    for (int off = 32; off; off >>= 1) {
        float mo = __shfl_xor(mp, off, 64), so = __shfl_xor(sp, off, 64);
        lse_merge(mp, sp, mo, so);
        float mo2 = __shfl_xor(mn, off, 64), so2 = __shfl_xor(sn, off, 64);
        lse_merge(mn, sn, mo2, so2);
    }
    if (lane == 0) {
        red[w][0] = mp; red[w][1] = sp; red[w][2] = mn; red[w][3] = sn;
    }
    __syncthreads();
    if (tid == 0) {
        mp = red[0][0]; sp = red[0][1]; mn = red[0][2]; sn = red[0][3];
        #pragma unroll
        for (int q = 1; q < 8; ++q) {
            lse_merge(mp, sp, red[q][0], red[q][1]);
            lse_merge(mn, sn, red[q][2], red[q][3]);
        }
        blockRes[bid] = make_float4(mp, sp, mn, sn);
    }
}

// ---- Kernel C: final reduction + softplus ----
__global__ __launch_bounds__(256)
void finalize_kernel(const float4* __restrict__ blockRes, int nb, float* __restrict__ out) {
    __shared__ float red[4][4];
    int tid = threadIdx.x;
    float mp = -1e30f, sp = 0.f, mn = -1e30f, sn = 0.f;
    for (int i = tid; i < nb; i += 256) {
        float4 v = blockRes[i];
        lse_merge(mp, sp, v.x, v.y);
        lse_merge(mn, sn, v.z, v.w);
    }
    #pragma unroll
    for (int off = 32; off; off >>= 1) {
        float mo = __shfl_xor(mp, off, 64), so = __shfl_xor(sp, off, 64);
        lse_merge(mp, sp, mo, so);
        float mo2 = __shfl_xor(mn, off, 64), so2 = __shfl_xor(sn, off, 64);
        lse_merge(mn, sn, mo2, so2);
    }
    int wid = tid >> 6;
    if ((tid & 63) == 0) {
        red[wid][0] = mp; red[wid][1] = sp; red[wid][2] = mn; red[wid][3] = sn;
    }
    __syncthreads();
    if (tid == 0) {
        mp = red[0][0]; sp = red[0][1]; mn = red[0][2]; sn = red[0][3];
        #pragma unroll
        for (int w = 1; w < 4; ++w) {
            lse_merge(mp, sp, red[w][0], red[w][1]);
            lse_merge(mn, sn, red[w][2], red[w][3]);
        }
        float lse_p = (sp > 0.f) ? mp + logf(sp) : -1e30f;
        float lse_n = (sn > 0.f) ? mn + logf(sn) : -1e30f;
        float x = lse_p + lse_n;
        float r = (x > 20.f) ? x : log1pf(expf(x));
        out[0] = r;
    }
}

extern "C" void kernel_launch(void* const* d_in, const int* in_sizes, int n_in,
                              void* d_out, int out_size, void* d_ws, size_t ws_size,
                              hipStream_t stream) {
    const float* f   = (const float*)d_in[0];
    const int*   lab = (const int*)d_in[1];
    float*  out      = (float*)d_out;

    __hip_bfloat16* fhi = (__hip_bfloat16*)d_ws;                       // 2 MB
    __hip_bfloat16* flo = (__hip_bfloat16*)((char*)d_ws + 2u * 1024 * 1024);   // 2 MB
    float4* blockRes    = (float4*)((char*)d_ws + 4u * 1024 * 1024);   // 64 KB

    prep_kernel<<<NROW / 4, 256, 0, stream>>>(f, fhi, flo);

    dim3 grid(NT, NT);
    sim_kernel<<<grid, 512, 0, stream>>>(fhi, flo, lab, blockRes);

    finalize_kernel<<<1, 256, 0, stream>>>(blockRes, NT * NT, out);
}

// Round 3
// 49.818 us; speedup vs baseline: 3.6587x; 1.7708x over previous
//
#include <hip/hip_runtime.h>
#include <hip/hip_bf16.h>
#include <math.h>

#define NROW 8192
#define DIM  128
#define BM   128
#define BN   128
#define NT   (NROW / BM)              // 64
#define NTILES ((NT * (NT + 1)) / 2)  // 2080

typedef __bf16 bf16x8 __attribute__((ext_vector_type(8)));
typedef float  f32x4  __attribute__((ext_vector_type(4)));

#define G2      369.3299304675746f    /* 256 * log2(e): logits in base-2 */
#define NEGBIG  (-3.0e38f)
#define NOFF    2000.0f               /* neg-class value offset for class-by-value */

// ---- Kernel A: normalize rows -> bf16 ----
__global__ __launch_bounds__(256)
void prep_kernel(const float* __restrict__ f, __hip_bfloat16* __restrict__ fhi) {
    int row  = blockIdx.x * 4 + (threadIdx.x >> 6);
    int lane = threadIdx.x & 63;
    float2 v = ((const float2*)(f + (size_t)row * DIM))[lane];
    float ss = v.x * v.x + v.y * v.y;
    #pragma unroll
    for (int off = 32; off; off >>= 1) ss += __shfl_xor(ss, off, 64);
    float inv = 1.0f / fmaxf(sqrtf(ss), 1e-12f);
    __hip_bfloat162 hv;
    hv.x = __float2bfloat16(v.x * inv);
    hv.y = __float2bfloat16(v.y * inv);
    ((__hip_bfloat162*)(fhi + (size_t)row * DIM))[lane] = hv;
}

// ---- Kernel B: MFMA sim + fused branchless two-pass LSE ----
__global__ __launch_bounds__(256, 4)
void sim_kernel(const __hip_bfloat16* __restrict__ fhi,
                const int* __restrict__ lab,
                float4* __restrict__ blockRes) {
    const int tid  = threadIdx.x;
    const int w    = tid >> 6;
    const int lane = tid & 63;
    const int lrow = lane & 15;
    const int lk   = lane >> 4;

    // triangular decode: bid -> (tr, tc), tc >= tr
    int bid = blockIdx.x;
    int tr = (int)((129.0f - sqrtf(16641.0f - 8.0f * (float)bid)) * 0.5f);
    while (tr > 0 && bid < tr * NT - (tr * (tr - 1)) / 2) --tr;
    while (bid >= (tr + 1) * NT - ((tr + 1) * tr) / 2) ++tr;
    const int tc = tr + (bid - (tr * NT - (tr * (tr - 1)) / 2));

    const int rowBase = tr * BM;
    const int colBase = tc * BN;

    __shared__ __align__(16) char smem[2 * 16384];  // A[128][64], B[128][64] bf16
    __shared__ int labA[BM];
    __shared__ int labB[BN];
    __shared__ float red[4][4];

    if (tid < BM) labA[tid] = lab[rowBase + tid];
    else          labB[tid - BM] = lab[colBase + (tid - BM)];

    f32x4 acc[4][4];
    #pragma unroll
    for (int mi = 0; mi < 4; ++mi)
        #pragma unroll
        for (int ni = 0; ni < 4; ++ni) acc[mi][ni] = (f32x4){0.f, 0.f, 0.f, 0.f};

    const int mrow0 = (w >> 1) * 64;   // 2x2 wave grid, 64x64 per wave
    const int ncol0 = (w & 1) * 64;

    const int rsub = lane >> 3;                   // row within 8-row segment
    const int kbs  = 16 * ((lane & 7) ^ rsub);    // pre-swizzled source byte (rule 21)

    for (int kc = 0; kc < 2; ++kc) {   // two K=64 chunks
        #pragma unroll
        for (int t = 0; t < 8; ++t) {
            int seg = w * 8 + t;          // 0..31
            int arr = seg >> 4;           // 0:A  1:B
            int s16 = seg & 15;           // 8-row segment
            char* ldsb = smem + arr * 16384 + s16 * 1024;
            int grow = (arr ? colBase : rowBase) + s16 * 8 + rsub;
            const char* g = (const char*)fhi + (size_t)grow * 256 + kc * 128 + kbs;
            __builtin_amdgcn_global_load_lds(
                (const __attribute__((address_space(1))) void*)g,
                (__attribute__((address_space(3))) void*)ldsb, 16, 0, 0);
        }
        __syncthreads();   // drains vmcnt before barrier

        const char* As = smem;
        const char* Bs = smem + 16384;
        #pragma unroll
        for (int c = 0; c < 2; ++c) {
            int kb = c * 64 + lk * 16;
            bf16x8 bfr[4];
            #pragma unroll
            for (int ni = 0; ni < 4; ++ni) {
                int rb = ncol0 + ni * 16 + lrow;
                bfr[ni] = *(const bf16x8*)(Bs + rb * 128 + (kb ^ ((rb & 7) << 4)));
            }
            #pragma unroll
            for (int mi = 0; mi < 4; ++mi) {
                int ra = mrow0 + mi * 16 + lrow;
                bf16x8 afr = *(const bf16x8*)(As + ra * 128 + (kb ^ ((ra & 7) << 4)));
                #pragma unroll
                for (int ni = 0; ni < 4; ++ni)
                    acc[mi][ni] = __builtin_amdgcn_mfma_f32_16x16x32_bf16(afr, bfr[ni], acc[mi][ni], 0, 0, 0);
            }
        }
        __syncthreads();   // before next chunk overwrites LDS
    }

    // ---- pass A: logits (base-2) in place + gated maxes ----
    float mp = NEGBIG, mn2 = NEGBIG;
    const bool diag = (tr == tc);

    int lbv[4];
    #pragma unroll
    for (int ni = 0; ni < 4; ++ni) lbv[ni] = labB[ncol0 + ni * 16 + lrow];

    #pragma unroll
    for (int mi = 0; mi < 4; ++mi) {
        const int il0 = mrow0 + mi * 16 + lk * 4;
        int4 la4 = *(const int4*)&labA[il0];
        const int la[4] = {la4.x, la4.y, la4.z, la4.w};
        #pragma unroll
        for (int ni = 0; ni < 4; ++ni) {
            const int jl = ncol0 + ni * 16 + lrow;
            #pragma unroll
            for (int r = 0; r < 4; ++r) {
                float s = acc[mi][ni][r];
                bool pos = (la[r] == lbv[ni]);
                // logit_p*log2e = max(1.25-s,0) * (0.75-s)*G2
                float lp = fmaxf(1.25f - s, 0.f) * fmaf(-G2, s, 0.75f * G2);
                // logit_n*log2e - 2000 = max(s+0.25,0)*(s-0.25)*G2 - 2000
                float ln2v = fmaf(fmaxf(s + 0.25f, 0.f), fmaf(G2, s, -0.25f * G2), -NOFF);
                if (diag) {
                    bool valid = (jl > il0 + r);   // strict upper triangle
                    lp   = valid ? lp   : NEGBIG;
                    ln2v = valid ? ln2v : NEGBIG;
                }
                mp  = fmaxf(mp,  pos ? lp : NEGBIG);
                mn2 = fmaxf(mn2, pos ? NEGBIG : ln2v);
                acc[mi][ni][r] = pos ? lp : ln2v;
            }
        }
    }

    // ---- block max reduce (plain fmax, no exp) ----
    #pragma unroll
    for (int off = 32; off; off >>= 1) {
        mp  = fmaxf(mp,  __shfl_xor(mp,  off, 64));
        mn2 = fmaxf(mn2, __shfl_xor(mn2, off, 64));
    }
    if (lane == 0) { red[w][0] = mp; red[w][1] = mn2; }
    __syncthreads();
    const float Mp  = fmaxf(fmaxf(red[0][0], red[1][0]), fmaxf(red[2][0], red[3][0]));
    const float Mn2 = fmaxf(fmaxf(red[0][1], red[1][1]), fmaxf(red[2][1], red[3][1]));

    // ---- pass B: one exp2 per element, class by value ----
    float sp = 0.f, sn = 0.f;
    #pragma unroll
    for (int mi = 0; mi < 4; ++mi)
        #pragma unroll
        for (int ni = 0; ni < 4; ++ni)
            #pragma unroll
            for (int r = 0; r < 4; ++r) {
                float x = acc[mi][ni][r];
                bool pos = (x > -1000.f);      // lp >= -35; ln2v <= -1650
                float m = pos ? Mp : Mn2;
                float e = __builtin_amdgcn_exp2f(x - m);
                float ep = pos ? e : 0.f;
                sp += ep;
                sn += (e - ep);
            }

    // ---- block sum reduce (plain adds) ----
    #pragma unroll
    for (int off = 32; off; off >>= 1) {
        sp += __shfl_xor(sp, off, 64);
        sn += __shfl_xor(sn, off, 64);
    }
    if (lane == 0) { red[w][2] = sp; red[w][3] = sn; }
    __syncthreads();
    if (tid == 0) {
        float Sp = red[0][2] + red[1][2] + red[2][2] + red[3][2];
        float Sn = red[0][3] + red[1][3] + red[2][3] + red[3][3];
        blockRes[bid] = make_float4(Mp, Sp, Mn2, Sn);
    }
}

// ---- Kernel C: merge block (m,s) pairs (base-2) + softplus ----
__device__ __forceinline__ void merge2(float& m, float& s, float mo, float so) {
    float M = fmaxf(m, mo);
    s = s * __builtin_amdgcn_exp2f(m - M) + so * __builtin_amdgcn_exp2f(mo - M);
    m = M;
}

__global__ __launch_bounds__(256)
void finalize_kernel(const float4* __restrict__ blockRes, float* __restrict__ out) {
    __shared__ float red[4][4];
    int tid = threadIdx.x;
    float mp = NEGBIG, sp = 0.f, mn = NEGBIG, sn = 0.f;
    for (int i = tid; i < NTILES; i += 256) {
        float4 v = blockRes[i];
        merge2(mp, sp, v.x, v.y);
        merge2(mn, sn, v.z, v.w);
    }
    #pragma unroll
    for (int off = 32; off; off >>= 1) {
        float mo = __shfl_xor(mp, off, 64), so = __shfl_xor(sp, off, 64);
        merge2(mp, sp, mo, so);
        float mo2 = __shfl_xor(mn, off, 64), so2 = __shfl_xor(sn, off, 64);
        merge2(mn, sn, mo2, so2);
    }
    int wv = tid >> 6;
    if ((tid & 63) == 0) {
        red[wv][0] = mp; red[wv][1] = sp; red[wv][2] = mn; red[wv][3] = sn;
    }
    __syncthreads();
    if (tid == 0) {
        mp = red[0][0]; sp = red[0][1]; mn = red[0][2]; sn = red[0][3];
        #pragma unroll
        for (int q = 1; q < 4; ++q) {
            merge2(mp, sp, red[q][0], red[q][1]);
            merge2(mn, sn, red[q][2], red[q][3]);
        }
        const double LN2 = 0.6931471805599453;
        double lse_p = ((double)mp + log2((double)sp)) * LN2;
        double lse_n = ((double)mn + (double)NOFF + log2((double)sn)) * LN2;
        double xx = lse_p + lse_n;
        double r = (xx > 30.0) ? xx : log1p(exp(xx));
        out[0] = (float)r;
    }
}

extern "C" void kernel_launch(void* const* d_in, const int* in_sizes, int n_in,
                              void* d_out, int out_size, void* d_ws, size_t ws_size,
                              hipStream_t stream) {
    const float* f   = (const float*)d_in[0];
    const int*   lab = (const int*)d_in[1];
    float*  out      = (float*)d_out;

    __hip_bfloat16* fhi = (__hip_bfloat16*)d_ws;                     // 2 MB
    float4* blockRes    = (float4*)((char*)d_ws + 4u * 1024 * 1024); // 2080 float4

    prep_kernel<<<NROW / 4, 256, 0, stream>>>(f, fhi);
    sim_kernel<<<NTILES, 256, 0, stream>>>(fhi, lab, blockRes);
    finalize_kernel<<<1, 256, 0, stream>>>(blockRes, out);
}

// Round 4
// 48.670 us; speedup vs baseline: 3.7450x; 1.0236x over previous
//
#include <hip/hip_runtime.h>
#include <hip/hip_bf16.h>
#include <math.h>

#define NROW 8192
#define DIM  128
#define BM   128
#define BN   128
#define NT   (NROW / BM)              // 64
#define NTILES ((NT * (NT + 1)) / 2)  // 2080

typedef __bf16 bf16x8 __attribute__((ext_vector_type(8)));
typedef float  f32x4  __attribute__((ext_vector_type(4)));

#define G2      369.3299304675746f    /* 256 * log2(e): logits in base-2 */
#define NEGBIG  (-3.0e38f)
#define NOFF    2000.0f               /* neg-class value offset for class-by-value */

// ---- Kernel A: normalize rows -> bf16 ----
__global__ __launch_bounds__(256)
void prep_kernel(const float* __restrict__ f, __hip_bfloat16* __restrict__ fhi) {
    int row  = blockIdx.x * 4 + (threadIdx.x >> 6);
    int lane = threadIdx.x & 63;
    float2 v = ((const float2*)(f + (size_t)row * DIM))[lane];
    float ss = v.x * v.x + v.y * v.y;
    #pragma unroll
    for (int off = 32; off; off >>= 1) ss += __shfl_xor(ss, off, 64);
    float inv = 1.0f / fmaxf(sqrtf(ss), 1e-12f);
    __hip_bfloat162 hv;
    hv.x = __float2bfloat16(v.x * inv);
    hv.y = __float2bfloat16(v.y * inv);
    ((__hip_bfloat162*)(fhi + (size_t)row * DIM))[lane] = hv;
}

// ---- Kernel B: MFMA sim + fused lean two-pass LSE ----
__global__ __launch_bounds__(256, 4)
void sim_kernel(const __hip_bfloat16* __restrict__ fhi,
                const int* __restrict__ lab,
                float4* __restrict__ blockRes) {
    const int tid  = threadIdx.x;
    const int w    = tid >> 6;
    const int lane = tid & 63;
    const int lrow = lane & 15;
    const int lk   = lane >> 4;

    // triangular decode: bid -> (tr, tc), tc >= tr
    int bid = blockIdx.x;
    int tr = (int)((129.0f - sqrtf(16641.0f - 8.0f * (float)bid)) * 0.5f);
    while (tr > 0 && bid < tr * NT - (tr * (tr - 1)) / 2) --tr;
    while (bid >= (tr + 1) * NT - ((tr + 1) * tr) / 2) ++tr;
    const int tc = tr + (bid - (tr * NT - (tr * (tr - 1)) / 2));

    const int rowBase = tr * BM;
    const int colBase = tc * BN;

    // [c0A][c0B][c1A][c1B], 16KB each: full K staged once, ONE barrier
    __shared__ __align__(16) char smem[4 * 16384];
    __shared__ int labA[BM];
    __shared__ int labB[BN];
    __shared__ float red[4][4];

    if (tid < BM) labA[tid] = lab[rowBase + tid];
    else          labB[tid - BM] = lab[colBase + (tid - BM)];

    f32x4 acc[4][4];
    #pragma unroll
    for (int mi = 0; mi < 4; ++mi)
        #pragma unroll
        for (int ni = 0; ni < 4; ++ni) acc[mi][ni] = (f32x4){0.f, 0.f, 0.f, 0.f};

    const int mrow0 = (w >> 1) * 64;   // 2x2 wave grid, 64x64 per wave
    const int ncol0 = (w & 1) * 64;

    const int rsub = lane >> 3;                   // row within 8-row segment
    const int kbs  = 16 * ((lane & 7) ^ rsub);    // pre-swizzled source byte (rule 21)

    // ---- stage ALL 64KB via global_load_lds (16 issues/wave) ----
    #pragma unroll
    for (int t = 0; t < 16; ++t) {
        int sg  = w * 16 + t;         // 0..63 segments of 1KB
        int arr = sg >> 4;            // 0:c0A 1:c0B 2:c1A 3:c1B
        int s16 = sg & 15;            // 8-row segment within array
        int kc  = arr >> 1;
        char* ldsb = smem + arr * 16384 + s16 * 1024;
        int grow = ((arr & 1) ? colBase : rowBase) + s16 * 8 + rsub;
        const char* g = (const char*)fhi + (size_t)grow * 256 + kc * 128 + kbs;
        __builtin_amdgcn_global_load_lds(
            (const __attribute__((address_space(1))) void*)g,
            (__attribute__((address_space(3))) void*)ldsb, 16, 0, 0);
    }
    __syncthreads();   // single barrier: drains vmcnt

    #pragma unroll
    for (int kc = 0; kc < 2; ++kc) {
        const char* As = smem + kc * 32768;
        const char* Bs = As + 16384;
        #pragma unroll
        for (int c = 0; c < 2; ++c) {
            int kb = c * 64 + lk * 16;
            bf16x8 bfr[4];
            #pragma unroll
            for (int ni = 0; ni < 4; ++ni) {
                int rb = ncol0 + ni * 16 + lrow;
                bfr[ni] = *(const bf16x8*)(Bs + rb * 128 + (kb ^ ((rb & 7) << 4)));
            }
            #pragma unroll
            for (int mi = 0; mi < 4; ++mi) {
                int ra = mrow0 + mi * 16 + lrow;
                bf16x8 afr = *(const bf16x8*)(As + ra * 128 + (kb ^ ((ra & 7) << 4)));
                #pragma unroll
                for (int ni = 0; ni < 4; ++ni)
                    acc[mi][ni] = __builtin_amdgcn_mfma_f32_16x16x32_bf16(afr, bfr[ni], acc[mi][ni], 0, 0, 0);
            }
        }
    }

    // ---- pass A: shared-s^2 logits + combined max ----
    const float Ppos = -2.0f * G2;
    const float Qpos = 0.9375f * G2;
    const float Qneg = -0.0625f * G2 - NOFF;
    float mall = NEGBIG, mneg = NEGBIG;
    const bool diag = (tr == tc);

    int lbv[4];
    #pragma unroll
    for (int ni = 0; ni < 4; ++ni) lbv[ni] = labB[ncol0 + ni * 16 + lrow];

    #pragma unroll
    for (int mi = 0; mi < 4; ++mi) {
        const int il0 = mrow0 + mi * 16 + lk * 4;
        int4 la4 = *(const int4*)&labA[il0];
        const int la[4] = {la4.x, la4.y, la4.z, la4.w};
        #pragma unroll
        for (int ni = 0; ni < 4; ++ni) {
            const int jl = ncol0 + ni * 16 + lrow;
            #pragma unroll
            for (int r = 0; r < 4; ++r) {
                float s = acc[mi][ni][r];
                bool pos = (la[r] == lbv[ni]);
                float P  = pos ? Ppos : 0.0f;
                float Qc = pos ? Qpos : Qneg;
                float base = fmaf(G2, s * s, fmaf(P, s, Qc));
                bool keep = pos || (s > -0.25f);
                float x = keep ? base : -NOFF;
                if (diag) x = (jl > il0 + r) ? x : NEGBIG;
                mall = fmaxf(mall, x);
                float xn = pos ? NEGBIG : x;
                mneg = fmaxf(mneg, xn);
                acc[mi][ni][r] = x;
            }
        }
    }

    // ---- block max reduce ----
    #pragma unroll
    for (int off = 32; off; off >>= 1) {
        mall = fmaxf(mall, __shfl_xor(mall, off, 64));
        mneg = fmaxf(mneg, __shfl_xor(mneg, off, 64));
    }
    if (lane == 0) { red[w][0] = mall; red[w][1] = mneg; }
    __syncthreads();
    const float mar = fmaxf(fmaxf(red[0][0], red[1][0]), fmaxf(red[2][0], red[3][0]));
    const float mnr = fmaxf(fmaxf(red[0][1], red[1][1]), fmaxf(red[2][1], red[3][1]));
    const float Mp  = (mar > -1000.f) ? mar : 0.f;      // no-pos guard
    const float Mn2 = (mnr > -2500.f) ? mnr : -1000.f;  // no-neg guard

    // ---- pass B: pos sum select-free (neg terms underflow to 0) ----
    float sp = 0.f, sn = 0.f;
    #pragma unroll
    for (int mi = 0; mi < 4; ++mi)
        #pragma unroll
        for (int ni = 0; ni < 4; ++ni)
            #pragma unroll
            for (int r = 0; r < 4; ++r) {
                float x = acc[mi][ni][r];
                sp += __builtin_amdgcn_exp2f(x - Mp);
                float xm = (x > -1000.f) ? NEGBIG : x;
                sn += __builtin_amdgcn_exp2f(xm - Mn2);
            }

    // ---- block sum reduce ----
    #pragma unroll
    for (int off = 32; off; off >>= 1) {
        sp += __shfl_xor(sp, off, 64);
        sn += __shfl_xor(sn, off, 64);
    }
    __syncthreads();   // red[] reuse
    if (lane == 0) { red[w][2] = sp; red[w][3] = sn; }
    __syncthreads();
    if (tid == 0) {
        float Sp = red[0][2] + red[1][2] + red[2][2] + red[3][2];
        float Sn = red[0][3] + red[1][3] + red[2][3] + red[3][3];
        blockRes[bid] = make_float4(Mp, Sp, Mn2, Sn);
    }
}

// ---- Kernel C: merge block (m,s) pairs (base-2) + softplus ----
__device__ __forceinline__ void merge2(float& m, float& s, float mo, float so) {
    float M = fmaxf(m, mo);
    s = s * __builtin_amdgcn_exp2f(m - M) + so * __builtin_amdgcn_exp2f(mo - M);
    m = M;
}

__global__ __launch_bounds__(256)
void finalize_kernel(const float4* __restrict__ blockRes, float* __restrict__ out) {
    __shared__ float red[4][4];
    int tid = threadIdx.x;
    float mp = NEGBIG, sp = 0.f, mn = NEGBIG, sn = 0.f;
    for (int i = tid; i < NTILES; i += 256) {
        float4 v = blockRes[i];
        merge2(mp, sp, v.x, v.y);
        merge2(mn, sn, v.z, v.w);
    }
    #pragma unroll
    for (int off = 32; off; off >>= 1) {
        float mo = __shfl_xor(mp, off, 64), so = __shfl_xor(sp, off, 64);
        merge2(mp, sp, mo, so);
        float mo2 = __shfl_xor(mn, off, 64), so2 = __shfl_xor(sn, off, 64);
        merge2(mn, sn, mo2, so2);
    }
    int wv = tid >> 6;
    if ((tid & 63) == 0) {
        red[wv][0] = mp; red[wv][1] = sp; red[wv][2] = mn; red[wv][3] = sn;
    }
    __syncthreads();
    if (tid == 0) {
        mp = red[0][0]; sp = red[0][1]; mn = red[0][2]; sn = red[0][3];
        #pragma unroll
        for (int q = 1; q < 4; ++q) {
            merge2(mp, sp, red[q][0], red[q][1]);
            merge2(mn, sn, red[q][2], red[q][3]);
        }
        const double LN2 = 0.6931471805599453;
        double lse_p = ((double)mp + log2((double)sp)) * LN2;
        double lse_n = ((double)mn + (double)NOFF + log2((double)sn)) * LN2;
        double xx = lse_p + lse_n;
        double r = (xx > 30.0) ? xx : log1p(exp(xx));
        out[0] = (float)r;
    }
}

extern "C" void kernel_launch(void* const* d_in, const int* in_sizes, int n_in,
                              void* d_out, int out_size, void* d_ws, size_t ws_size,
                              hipStream_t stream) {
    const float* f   = (const float*)d_in[0];
    const int*   lab = (const int*)d_in[1];
    float*  out      = (float*)d_out;

    __hip_bfloat16* fhi = (__hip_bfloat16*)d_ws;                     // 2 MB
    float4* blockRes    = (float4*)((char*)d_ws + 4u * 1024 * 1024); // 2080 float4

    prep_kernel<<<NROW / 4, 256, 0, stream>>>(f, fhi);
    sim_kernel<<<NTILES, 256, 0, stream>>>(fhi, lab, blockRes);
    finalize_kernel<<<1, 256, 0, stream>>>(blockRes, out);
}

// Round 5
// 44.979 us; speedup vs baseline: 4.0523x; 1.0821x over previous
//
#include <hip/hip_runtime.h>
#include <hip/hip_bf16.h>
#include <math.h>

#define NROW 8192
#define DIM  128
#define BM   64
#define BN   128
#define TM   (NROW / BM)    // 128 row tiles
#define TN   (NROW / BN)    // 64 col tiles
#define NTILES 4160         // sum_{tr<128} (64 - (tr>>1))

typedef __bf16 bf16x8 __attribute__((ext_vector_type(8)));
typedef float  f32x4  __attribute__((ext_vector_type(4)));

#define G2      369.3299304675746f    /* 256 * log2(e): logits in base-2 */
#define NEGBIG  (-3.0e38f)
#define NOFF    2000.0f               /* neg-class value offset for class-by-value */

// ---- Kernel A: normalize rows -> bf16 ----
__global__ __launch_bounds__(256)
void prep_kernel(const float* __restrict__ f, __hip_bfloat16* __restrict__ fhi) {
    int row  = blockIdx.x * 4 + (threadIdx.x >> 6);
    int lane = threadIdx.x & 63;
    float2 v = ((const float2*)(f + (size_t)row * DIM))[lane];
    float ss = v.x * v.x + v.y * v.y;
    #pragma unroll
    for (int off = 32; off; off >>= 1) ss += __shfl_xor(ss, off, 64);
    float inv = 1.0f / fmaxf(sqrtf(ss), 1e-12f);
    __hip_bfloat162 hv;
    hv.x = __float2bfloat16(v.x * inv);
    hv.y = __float2bfloat16(v.y * inv);
    ((__hip_bfloat162*)(fhi + (size_t)row * DIM))[lane] = hv;
}

// first linear bid of row-tile tr (tc starts at tr>>1)
__device__ __forceinline__ int tstart(int tr) {
    int m = tr >> 1;
    int f = m * m - ((tr & 1) ? 0 : m);
    return 64 * tr - f;
}

// ---- Kernel B: MFMA sim + fused two-pass LSE (occupancy-tiled) ----
__global__ __launch_bounds__(256, 4)
void sim_kernel(const __hip_bfloat16* __restrict__ fhi,
                const int* __restrict__ lab,
                float4* __restrict__ blockRes) {
    const int tid  = threadIdx.x;
    const int w    = tid >> 6;
    const int lane = tid & 63;
    const int lrow = lane & 15;
    const int lk   = lane >> 4;

    // triangular decode: bid -> (tr, tc), tc >= tr>>1
    int bid = blockIdx.x;
    float sa = fmaxf(16384.f - 4.f * (float)bid, 0.f);
    int tr = 128 - (int)sqrtf(sa);
    if (tr > 127) tr = 127;
    if (tr < 0) tr = 0;
    while (tr > 0 && bid < tstart(tr)) --tr;
    while (bid >= tstart(tr + 1)) ++tr;
    const int tc = (tr >> 1) + (bid - tstart(tr));

    const int rowBase = tr * BM;
    const int colBase = tc * BN;

    // per chunk: A[64][64] bf16 (8KB) + B[128][64] bf16 (16KB), single-buffered
    __shared__ __align__(16) char smem[24 * 1024];
    __shared__ int labA[BM];
    __shared__ int labB[BN];
    __shared__ float red[4][4];

    if (tid < BM)                 labA[tid] = lab[rowBase + tid];
    else if (tid < BM + BN)       labB[tid - BM] = lab[colBase + (tid - BM)];

    f32x4 acc[4][2];
    #pragma unroll
    for (int mi = 0; mi < 4; ++mi)
        #pragma unroll
        for (int ni = 0; ni < 2; ++ni) acc[mi][ni] = (f32x4){0.f, 0.f, 0.f, 0.f};

    const int ncol0 = w * 32;                     // 1x4 wave grid: 64x32 per wave

    const int rsub = lane >> 3;                   // row within 8-row segment
    const int kbs  = 16 * ((lane & 7) ^ rsub);    // pre-swizzled source byte (rule 21)

    for (int kc = 0; kc < 2; ++kc) {   // two K=64 chunks
        #pragma unroll
        for (int t = 0; t < 6; ++t) {
            int seg = w * 6 + t;          // 0..23 segments of 1KB (A:0-7, B:8-23)
            char* ldsb = smem + seg * 1024;
            int grow = (seg < 8) ? (rowBase + (seg & 7) * 8 + rsub)
                                 : (colBase + (seg - 8) * 8 + rsub);
            const char* g = (const char*)fhi + (size_t)grow * 256 + kc * 128 + kbs;
            __builtin_amdgcn_global_load_lds(
                (const __attribute__((address_space(1))) void*)g,
                (__attribute__((address_space(3))) void*)ldsb, 16, 0, 0);
        }
        __syncthreads();   // drains vmcnt

        const char* As = smem;
        const char* Bs = smem + 8192;
        #pragma unroll
        for (int c = 0; c < 2; ++c) {
            int kb = c * 64 + lk * 16;
            bf16x8 bfr[2];
            #pragma unroll
            for (int ni = 0; ni < 2; ++ni) {
                int rb = ncol0 + ni * 16 + lrow;
                bfr[ni] = *(const bf16x8*)(Bs + rb * 128 + (kb ^ ((rb & 7) << 4)));
            }
            #pragma unroll
            for (int mi = 0; mi < 4; ++mi) {
                int ra = mi * 16 + lrow;
                bf16x8 afr = *(const bf16x8*)(As + ra * 128 + (kb ^ ((ra & 7) << 4)));
                #pragma unroll
                for (int ni = 0; ni < 2; ++ni)
                    acc[mi][ni] = __builtin_amdgcn_mfma_f32_16x16x32_bf16(afr, bfr[ni], acc[mi][ni], 0, 0, 0);
            }
        }
        __syncthreads();   // before next chunk overwrites LDS
    }

    // ---- pass A: quadratic logits (base-2, neg offset by -NOFF) + maxes ----
    const float Ppos = -2.0f * G2;
    const float Qpos = 0.9375f * G2;
    const float Qneg = -0.0625f * G2 - NOFF;
    float mall = NEGBIG, mneg = NEGBIG;
    const bool edge = (tc == (tr >> 1));   // only tiles straddling the diagonal

    int lbv[2];
    #pragma unroll
    for (int ni = 0; ni < 2; ++ni) lbv[ni] = labB[ncol0 + ni * 16 + lrow];

    #pragma unroll
    for (int mi = 0; mi < 4; ++mi) {
        int4 la4 = *(const int4*)&labA[mi * 16 + lk * 4];
        const int la[4] = {la4.x, la4.y, la4.z, la4.w};
        #pragma unroll
        for (int ni = 0; ni < 2; ++ni) {
            const int jg = colBase + ncol0 + ni * 16 + lrow;
            #pragma unroll
            for (int r = 0; r < 4; ++r) {
                float s = acc[mi][ni][r];
                bool pos = (la[r] == lbv[ni]);
                float P  = pos ? Ppos : 0.0f;
                float Qc = pos ? Qpos : Qneg;
                float base = fmaf(G2, s * s, fmaf(P, s, Qc));
                bool keep = pos || (s > -0.25f);
                float x = keep ? base : -NOFF;
                if (edge) {
                    int ig = rowBase + mi * 16 + lk * 4 + r;
                    x = (jg > ig) ? x : NEGBIG;   // strict upper triangle
                }
                mall = fmaxf(mall, x);
                mneg = fmaxf(mneg, pos ? NEGBIG : x);
                acc[mi][ni][r] = x;
            }
        }
    }

    // ---- block max reduce ----
    #pragma unroll
    for (int off = 32; off; off >>= 1) {
        mall = fmaxf(mall, __shfl_xor(mall, off, 64));
        mneg = fmaxf(mneg, __shfl_xor(mneg, off, 64));
    }
    if (lane == 0) { red[w][0] = mall; red[w][1] = mneg; }
    __syncthreads();
    const float mar = fmaxf(fmaxf(red[0][0], red[1][0]), fmaxf(red[2][0], red[3][0]));
    const float mnr = fmaxf(fmaxf(red[0][1], red[1][1]), fmaxf(red[2][1], red[3][1]));
    const float Mp  = (mar > -1000.f) ? mar : 0.f;      // no-pos guard
    const float Mn2 = (mnr > -2500.f) ? mnr : -1000.f;  // no-neg guard

    // ---- pass B: ONE exp2 per element, class-selected max ----
    float sp = 0.f, sn = 0.f;
    #pragma unroll
    for (int mi = 0; mi < 4; ++mi)
        #pragma unroll
        for (int ni = 0; ni < 2; ++ni)
            #pragma unroll
            for (int r = 0; r < 4; ++r) {
                float x = acc[mi][ni][r];
                bool p2 = (x > -1000.f);
                float Ms = p2 ? Mp : Mn2;
                float e = __builtin_amdgcn_exp2f(x - Ms);
                float ep = p2 ? e : 0.f;
                sp += ep;
                sn += (e - ep);
            }

    // ---- block sum reduce ----
    #pragma unroll
    for (int off = 32; off; off >>= 1) {
        sp += __shfl_xor(sp, off, 64);
        sn += __shfl_xor(sn, off, 64);
    }
    __syncthreads();   // red[] reuse
    if (lane == 0) { red[w][2] = sp; red[w][3] = sn; }
    __syncthreads();
    if (tid == 0) {
        float Sp = red[0][2] + red[1][2] + red[2][2] + red[3][2];
        float Sn = red[0][3] + red[1][3] + red[2][3] + red[3][3];
        blockRes[bid] = make_float4(Mp, Sp, Mn2, Sn);
    }
}

// ---- Kernel C: merge block (m,s) pairs (base-2) + softplus ----
__device__ __forceinline__ void merge2(float& m, float& s, float mo, float so) {
    float M = fmaxf(m, mo);
    s = s * __builtin_amdgcn_exp2f(m - M) + so * __builtin_amdgcn_exp2f(mo - M);
    m = M;
}

__global__ __launch_bounds__(256)
void finalize_kernel(const float4* __restrict__ blockRes, float* __restrict__ out) {
    __shared__ float red[4][4];
    int tid = threadIdx.x;
    float mp = NEGBIG, sp = 0.f, mn = NEGBIG, sn = 0.f;
    for (int i = tid; i < NTILES; i += 256) {
        float4 v = blockRes[i];
        merge2(mp, sp, v.x, v.y);
        merge2(mn, sn, v.z, v.w);
    }
    #pragma unroll
    for (int off = 32; off; off >>= 1) {
        float mo = __shfl_xor(mp, off, 64), so = __shfl_xor(sp, off, 64);
        merge2(mp, sp, mo, so);
        float mo2 = __shfl_xor(mn, off, 64), so2 = __shfl_xor(sn, off, 64);
        merge2(mn, sn, mo2, so2);
    }
    int wv = tid >> 6;
    if ((tid & 63) == 0) {
        red[wv][0] = mp; red[wv][1] = sp; red[wv][2] = mn; red[wv][3] = sn;
    }
    __syncthreads();
    if (tid == 0) {
        mp = red[0][0]; sp = red[0][1]; mn = red[0][2]; sn = red[0][3];
        #pragma unroll
        for (int q = 1; q < 4; ++q) {
            merge2(mp, sp, red[q][0], red[q][1]);
            merge2(mn, sn, red[q][2], red[q][3]);
        }
        const double LN2 = 0.6931471805599453;
        double lse_p = ((double)mp + log2((double)sp)) * LN2;
        double lse_n = ((double)mn + (double)NOFF + log2((double)sn)) * LN2;
        double xx = lse_p + lse_n;
        double r = (xx > 30.0) ? xx : log1p(exp(xx));
        out[0] = (float)r;
    }
}

extern "C" void kernel_launch(void* const* d_in, const int* in_sizes, int n_in,
                              void* d_out, int out_size, void* d_ws, size_t ws_size,
                              hipStream_t stream) {
    const float* f   = (const float*)d_in[0];
    const int*   lab = (const int*)d_in[1];
    float*  out      = (float*)d_out;

    __hip_bfloat16* fhi = (__hip_bfloat16*)d_ws;                     // 2 MB
    float4* blockRes    = (float4*)((char*)d_ws + 4u * 1024 * 1024); // 4160 float4

    prep_kernel<<<NROW / 4, 256, 0, stream>>>(f, fhi);
    sim_kernel<<<NTILES, 256, 0, stream>>>(fhi, lab, blockRes);
    finalize_kernel<<<1, 256, 0, stream>>>(blockRes, out);
}